// Round 5
// baseline (3105.105 us; speedup 1.0000x reference)
//
#include <hip/hip_runtime.h>
#include <hip/hip_bf16.h>
#include <hip/hip_fp16.h>
#include <math.h>

#define BB 64
#define SS 512
#define TT 48
#define EE 300
#define EP 320   // E padded (160 k-pairs)
#define KP 160   // k-pairs per row
#define HH 256
#define G4 1024  // 4*H
#define NG 2048  // both directions
#define NEGV -10000.0f

// k_lstm: 1024 threads, thread owns one gate column; 32 uint4 weights in VGPRs
#define WPK_U 131072   // uints per dir = 32 q4 * 1024 cols * 4

__device__ __forceinline__ float sigf(float x) { return 1.0f / (1.0f + __expf(-x)); }
__device__ __forceinline__ float tanhf_(float x) {
    float e = __expf(2.0f * x);          // inf-safe
    return 1.0f - 2.0f / (e + 1.0f);
}

__device__ __forceinline__ float dot2u(unsigned int h, unsigned int w, float acc) {
#if __has_builtin(__builtin_amdgcn_fdot2)
    typedef _Float16 h2v __attribute__((ext_vector_type(2)));
    union { unsigned int u; h2v v; } H, W;
    H.u = h; W.u = w;
    return __builtin_amdgcn_fdot2(H.v, W.v, acc, false);
#else
    __half2 hh = *(__half2*)&h, ww = *(__half2*)&w;
    float2 hf = __half22float2(hh), wf = __half22float2(ww);
    return acc + hf.x * wf.x + hf.y * wf.y;
#endif
}

__device__ __forceinline__ unsigned int packh2(float lo, float hi) {
    union { __half2 h; unsigned int u; } p;
    p.h = __floats2half2_rn(lo, hi);
    return p.u;
}

// ---------------- prep ----------------
// Gate-interleaved column order: col c = 4j+q  <->  source row q*256+j
// WIHTP: [160][2048] uint  (k-pair packed, permuted cols, zero-padded K)
// BIAS:  [2048] fp32 (permuted)
// WPK:   [dir][32][1024] uint4; component x of (q4,c) = Whh k-pair (8q4+2x) of col c
// WOT:   [512][T] fp32
__global__ __launch_bounds__(256) void k_prep(
    const float* __restrict__ Whh_f, const float* __restrict__ Whh_b,
    const float* __restrict__ Wih_f, const float* __restrict__ Wih_b,
    const float* __restrict__ bih_f, const float* __restrict__ bhh_f,
    const float* __restrict__ bih_b, const float* __restrict__ bhh_b,
    const float* __restrict__ W_out,
    unsigned int* __restrict__ WIHTP, float* __restrict__ BIAS,
    unsigned int* __restrict__ WPK, float* __restrict__ WOT)
{
    int i = blockIdx.x * 256 + threadIdx.x;
    const int NWIHP = KP * NG;     // 327680
    if (i < NWIHP) {
        int kp = i >> 11, n = i & 2047; int d = n >> 10, c = n & 1023;
        int row = (c & 3) * 256 + (c >> 2);
        const float* w = d ? Wih_b : Wih_f;
        int k0 = 2 * kp, k1 = 2 * kp + 1;
        WIHTP[i] = packh2(k0 < EE ? w[row * EE + k0] : 0.0f,
                          k1 < EE ? w[row * EE + k1] : 0.0f);
        return;
    }
    i -= NWIHP;
    if (i < NG) {
        int d = i >> 10, c = i & 1023;
        int row = (c & 3) * 256 + (c >> 2);
        BIAS[i] = d ? (bih_b[row] + bhh_b[row]) : (bih_f[row] + bhh_f[row]);
        return;
    }
    i -= NG;
    if (i < 2 * WPK_U) {
        int d = i / WPK_U, uu = i % WPK_U;
        int q4 = uu >> 12, rem = uu & 4095, c = rem >> 2, x = rem & 3;
        int row = (c & 3) * 256 + (c >> 2);
        int k = 8 * q4 + 2 * x;
        const float* W = d ? Whh_b : Whh_f;
        WPK[i] = packh2(W[row * HH + k], W[row * HH + k + 1]);
        return;
    }
    i -= 2 * WPK_U;
    if (i < 512 * TT) { int k = i / TT, t = i % TT; WOT[i] = W_out[t * 512 + k]; return; }
}

// ---------------- embedding gather + concat + pad ----------------
__global__ __launch_bounds__(320) void k_embed(
    const int* __restrict__ wid, const int* __restrict__ fid, const int* __restrict__ pid,
    const float* __restrict__ ew, const float* __restrict__ ef, const float* __restrict__ ep,
    __half* __restrict__ X)
{
    int sb = blockIdx.x; int s = sb >> 6, b = sb & 63;
    int t = threadIdx.x;
    int w = wid[b * SS + s];
    int f = fid[b * SS + s];
    int p = pid[b * SS + s];
    float v;
    if (t < 200)      v = ew[w * 200 + t];
    else if (t < 250) v = ef[f * 50 + (t - 200)];
    else if (t < 300) v = ep[p * 50 + (t - 250)];
    else              v = 0.0f;
    X[(size_t)sb * EP + t] = __float2half(v);
}

// ---------------- input GEMM (fp16 dot2): GX = X * WIHT + BIAS ----------
// XP: X rows viewed as k-pairs [32768][160]; WP: [160][2048] k-pairs
__global__ __launch_bounds__(256) void k_gemm(
    const unsigned int* __restrict__ XP, const unsigned int* __restrict__ WP,
    const float* __restrict__ BIAS, __half* __restrict__ GX)
{
    __shared__ unsigned int Al[8][68];   // [kp][m], +4 pad
    __shared__ unsigned int Bl[8][68];   // [kp][n], +4 pad
    int tid = threadIdx.x;
    int tx = tid & 15, ty = tid >> 4;
    int m0 = blockIdx.y * 64, n0 = blockIdx.x * 64;
    int r = tid >> 2, q = tid & 3;         // A staging
    int bkp = tid >> 5, bc = (tid & 31) * 2; // B staging
    float acc[4][4] = {};
    for (int kp0 = 0; kp0 < KP; kp0 += 8) {
        uint2 a2 = *(const uint2*)(XP + (size_t)(m0 + r) * KP + kp0 + 2 * q);
        Al[2 * q][r] = a2.x; Al[2 * q + 1][r] = a2.y;
        uint2 b2 = *(const uint2*)(WP + (size_t)(kp0 + bkp) * NG + n0 + bc);
        *(uint2*)&Bl[bkp][bc] = b2;
        __syncthreads();
        #pragma unroll
        for (int kp = 0; kp < 8; kp++) {
            uint4 au = *(const uint4*)&Al[kp][ty * 4];
            uint4 bu = *(const uint4*)&Bl[kp][tx * 4];
            acc[0][0] = dot2u(au.x, bu.x, acc[0][0]); acc[0][1] = dot2u(au.x, bu.y, acc[0][1]);
            acc[0][2] = dot2u(au.x, bu.z, acc[0][2]); acc[0][3] = dot2u(au.x, bu.w, acc[0][3]);
            acc[1][0] = dot2u(au.y, bu.x, acc[1][0]); acc[1][1] = dot2u(au.y, bu.y, acc[1][1]);
            acc[1][2] = dot2u(au.y, bu.z, acc[1][2]); acc[1][3] = dot2u(au.y, bu.w, acc[1][3]);
            acc[2][0] = dot2u(au.z, bu.x, acc[2][0]); acc[2][1] = dot2u(au.z, bu.y, acc[2][1]);
            acc[2][2] = dot2u(au.z, bu.z, acc[2][2]); acc[2][3] = dot2u(au.z, bu.w, acc[2][3]);
            acc[3][0] = dot2u(au.w, bu.x, acc[3][0]); acc[3][1] = dot2u(au.w, bu.y, acc[3][1]);
            acc[3][2] = dot2u(au.w, bu.z, acc[3][2]); acc[3][3] = dot2u(au.w, bu.w, acc[3][3]);
        }
        __syncthreads();
    }
    float4 bias = *(const float4*)(BIAS + n0 + tx * 4);
    #pragma unroll
    for (int i = 0; i < 4; i++) {
        float2 lo = make_float2(acc[i][0] + bias.x, acc[i][1] + bias.y);
        float2 hi = make_float2(acc[i][2] + bias.z, acc[i][3] + bias.w);
        union { float2 f2; __half2 h2[2]; } u;
        u.h2[0] = __floats2half2_rn(lo.x, lo.y);
        u.h2[1] = __floats2half2_rn(hi.x, hi.y);
        *(float2*)(GX + (size_t)(m0 + ty * 4 + i) * NG + n0 + tx * 4) = u.f2;
    }
}

// ---------------- recurrent LSTM ----------------
// 128 wgs (dir,b) x 1024 threads (16 waves, 4/SIMD). Thread c owns gate
// column c (= gate q of unit j, c=4j+q). 32 uint4 weights in VGPRs (~128).
// LDS: only h double-buffer (1 KB). One barrier/step.
__global__ __launch_bounds__(1024, 4) void k_lstm(
    const uint4* __restrict__ WPK4, const __half* __restrict__ GX,
    const float* __restrict__ h0, const float* __restrict__ c0,
    __half* __restrict__ HS)
{
    __shared__ __align__(16) unsigned int hb[2][128];   // h as fp16 pairs
    int wg = blockIdx.x; int dir = wg >> 6, b = wg & 63;
    int c = threadIdx.x;
    int j = c >> 2, q = c & 3;

    const uint4* wp = WPK4 + (size_t)dir * (32 * 1024);
    uint4 WR[32];
    #pragma unroll
    for (int p = 0; p < 32; p++) {
        WR[p] = wp[p * 1024 + c];
        asm volatile("" : "+v"(WR[p].x), "+v"(WR[p].y), "+v"(WR[p].z), "+v"(WR[p].w));
    }

    size_t sbase = (size_t)dir * BB * HH + b * HH;
    float cst = c0[sbase + j];          // all 4 lanes of the quad keep unit j's c
    if (c < 128) hb[0][c] = packh2(h0[sbase + 2 * c], h0[sbase + 2 * c + 1]);
    __syncthreads();

    int s0 = dir ? (SS - 1) : 0;
    float gxf = __half2float(GX[(size_t)(s0 * BB + b) * NG + (dir << 10) + c]);

    int cur = 0;
    for (int t = 0; t < SS; t++) {
        int s  = dir ? (SS - 1 - t) : t;
        int tn = (t + 1 < SS) ? (t + 1) : t;
        int sn = dir ? (SS - 1 - tn) : tn;
        float gx_next = __half2float(GX[(size_t)(sn * BB + b) * NG + (dir << 10) + c]);

        float acc = gxf;
        const unsigned int* hbc = hb[cur];
        #pragma unroll
        for (int p = 0; p < 32; p++) {
            uint4 h4 = *(const uint4*)&hbc[4 * p];   // wave-broadcast 16B
            acc = dot2u(h4.x, WR[p].x, acc);
            acc = dot2u(h4.y, WR[p].y, acc);
            acc = dot2u(h4.z, WR[p].z, acc);
            acc = dot2u(h4.w, WR[p].w, acc);
        }

        // quad butterfly: all lanes reconstruct (i,f,g,o) of unit j
        float v0 = acc;
        float v1 = __shfl_xor(acc, 1);
        float v2 = __shfl_xor(acc, 2);
        float v3 = __shfl_xor(v1, 2);
        if (q & 1) { float t0 = v0; v0 = v1; v1 = t0; float t1 = v2; v2 = v3; v3 = t1; }
        if (q & 2) { float t0 = v0; v0 = v2; v2 = t0; float t1 = v1; v1 = v3; v3 = t1; }
        // v0=i, v1=f, v2=g, v3=o
        cst = sigf(v1) * cst + sigf(v0) * tanhf_(v2);
        float h = sigf(v3) * tanhf_(cst);

        float hn = __shfl_down(h, 4);            // unit j+1's h (lane c+4, same wave)
        if ((c & 7) == 0) hb[cur ^ 1][c >> 3] = packh2(h, hn);
        if (q == 0) HS[(size_t)(s * BB + b) * 512 + (dir << 8) + j] = __float2half(h);
        __syncthreads();
        cur ^= 1;
        gxf = gx_next;
    }
}

// ---------------- feats: [32768][48] = HS * WOT + b_out ------------------
__global__ __launch_bounds__(384) void k_feats(
    const __half* __restrict__ HS, const float* __restrict__ WOT,
    const float* __restrict__ b_out, float* __restrict__ F)
{
    __shared__ float rl[8 * 512];
    int sb0 = blockIdx.x * 8;
    int tid = threadIdx.x;
    for (int i = tid; i < 8 * 512; i += 384)
        rl[i] = __half2float(HS[(size_t)sb0 * 512 + i]);
    __syncthreads();
    int r = tid / TT, t = tid % TT;
    if (r < 8) {
        float acc = b_out[t];
        const float* rp = &rl[r * 512];
        #pragma unroll 8
        for (int k = 0; k < 512; k++)
            acc += rp[k] * WOT[k * TT + t];
        F[(size_t)(sb0 + r) * TT + t] = acc;
    }
}

// ---------------- Viterbi + backtrace: one wg per batch ------------------
__global__ __launch_bounds__(64) void k_viterbi(
    const float* __restrict__ F, const float* __restrict__ trans,
    float* __restrict__ out)
{
    int b = blockIdx.x;
    int tid = threadIdx.x;
    __shared__ float tl[TT * TT];        // transposed: tl[prev*T+next]
    __shared__ float fv[TT];
    __shared__ unsigned char bp[SS * TT];
    __shared__ unsigned char path[SS];
    for (int i = tid; i < TT * TT; i += 64) {
        int prev = i / TT, nx = i % TT;
        tl[i] = trans[nx * TT + prev];
    }
    if (tid < TT) fv[tid] = NEGV;
    __syncthreads();
    for (int s = 0; s < SS; s++) {
        float best = -1e30f; int bi = 0; float nf = 0.0f;
        if (tid < TT) {
            #pragma unroll 4
            for (int prev = 0; prev < TT; prev++) {
                float sc = fv[prev] + tl[prev * TT + tid];
                if (sc > best) { best = sc; bi = prev; }
            }
            nf = best + F[(size_t)(s * BB + b) * TT + tid];
            bp[s * TT + tid] = (unsigned char)bi;
        }
        __syncthreads();
        if (tid < TT) fv[tid] = nf;
        __syncthreads();
    }
    if (tid == 0) {
        float best = fv[0]; int bi = 0;
        for (int i = 1; i < TT; i++) if (fv[i] > best) { best = fv[i]; bi = i; }
        out[b] = best;
        int tag = bi;
        path[SS - 1] = (unsigned char)tag;
        for (int jj = SS - 2; jj >= 0; jj--) {
            tag = bp[(jj + 1) * TT + tag];
            path[jj] = (unsigned char)tag;
        }
    }
    __syncthreads();
    for (int jj = tid; jj < SS; jj += 64)
        out[BB + (size_t)b * SS + jj] = (float)path[jj];
}

extern "C" void kernel_launch(void* const* d_in, const int* in_sizes, int n_in,
                              void* d_out, int out_size, void* d_ws, size_t ws_size,
                              hipStream_t stream) {
    const int*   wid    = (const int*)d_in[0];
    const int*   fid    = (const int*)d_in[1];
    const int*   pid    = (const int*)d_in[2];
    const float* ew     = (const float*)d_in[3];
    const float* ef     = (const float*)d_in[4];
    const float* epn    = (const float*)d_in[5];
    const float* Wih_f  = (const float*)d_in[6];
    const float* Whh_f  = (const float*)d_in[7];
    const float* bih_f  = (const float*)d_in[8];
    const float* bhh_f  = (const float*)d_in[9];
    const float* Wih_b  = (const float*)d_in[10];
    const float* Whh_b  = (const float*)d_in[11];
    const float* bih_b  = (const float*)d_in[12];
    const float* bhh_b  = (const float*)d_in[13];
    const float* h0     = (const float*)d_in[14];
    const float* c0     = (const float*)d_in[15];
    const float* W_out  = (const float*)d_in[16];
    const float* b_out  = (const float*)d_in[17];
    const float* trans  = (const float*)d_in[18];

    char* p = (char*)d_ws;
    auto alloc = [&](size_t bytes) { char* r = p; p += (bytes + 255) & ~(size_t)255; return r; };
    __half*       X     = (__half*)alloc((size_t)32768 * EP * 2);       //  21.0 MB
    __half*       GX    = (__half*)alloc((size_t)32768 * NG * 2);       // 134.2 MB
    __half*       HS    = (__half*)alloc((size_t)32768 * 512 * 2);      //  33.6 MB
    unsigned int* WPK   = (unsigned int*)alloc((size_t)2 * WPK_U * 4);  //   1.0 MB
    unsigned int* WIHTP = (unsigned int*)alloc((size_t)KP * NG * 4);    //   1.3 MB
    float*        BIAS  = (float*)alloc((size_t)NG * 4);                //   8 KB
    float*        WOT   = (float*)alloc((size_t)512 * TT * 4);          //  98 KB
    float*        F     = (float*)alloc((size_t)32768 * TT * 4);        //   6.3 MB

    // k_prep elements: 327680 + 2048 + 262144 + 24576 = 616448
    k_prep<<<2408, 256, 0, stream>>>(Whh_f, Whh_b, Wih_f, Wih_b,
                                     bih_f, bhh_f, bih_b, bhh_b, W_out,
                                     WIHTP, BIAS, WPK, WOT);
    k_embed<<<32768, 320, 0, stream>>>(wid, fid, pid, ew, ef, epn, X);
    k_gemm<<<dim3(32, 512), 256, 0, stream>>>((const unsigned int*)X, WIHTP, BIAS, GX);
    k_lstm<<<128, 1024, 0, stream>>>((const uint4*)WPK, GX, h0, c0, HS);
    k_feats<<<4096, 384, 0, stream>>>(HS, WOT, b_out, F);
    k_viterbi<<<64, 64, 0, stream>>>(F, trans, (float*)d_out);
}